// Round 3
// baseline (766.523 us; speedup 1.0000x reference)
//
#include <hip/hip_runtime.h>
#include <math.h>

#define KST 9
#define CTC_BLANK 1
#define RBW 132  // row-buffer stride: 128 classes + zero slot at [128]

__device__ __forceinline__ void ctc_gath(float (&dst)[KST], const float* __restrict__ buf,
                                         const int (&e4)[KST]) {
#pragma unroll
  for (int s = 0; s < KST; ++s) dst[s] = buf[e4[s]];
}

__device__ __forceinline__ void ctc_upd(double (&a)[KST], const float (&p)[KST],
                                        const double (&sk)[KST], int lane) {
  double hm1 = __shfl_up(a[KST - 1], 1);
  double hm2 = __shfl_up(a[KST - 2], 1);
  if (lane == 0) { hm1 = 0.; hm2 = 0.; }
#pragma unroll
  for (int s = KST - 1; s >= 2; --s)
    a[s] = fma(sk[s], a[s - 2], a[s] + a[s - 1]) * (double)p[s];
  a[1] = fma(sk[1], hm1, a[1] + a[0]) * (double)p[1];
  a[0] = fma(sk[0], hm2, a[0] + hm1) * (double)p[0];
}

// One step: stage row t0+J+1 (from prefetch reg), refill prefetch (row t0+J+9),
// gather p for NEXT step, update alpha with p gathered LAST step.
#define CTC_STEP(J, PC, PN)                                                \
  {                                                                        \
    float* bufn = rb + RBW * ((J) & 1);                                    \
    float ex = __expf(pre[J].x);                                           \
    float ey = __expf(pre[J].y);                                           \
    bufn[2 * lane] = ex;                                                   \
    bufn[2 * lane + 1] = ey;                                               \
    {                                                                      \
      int tl_ = t0 + (J) + 9;                                              \
      if (tl_ > Tlast) tl_ = Tlast;                                        \
      pre[J] = *(const float2*)(lpn + (size_t)tl_ * NC + 2 * lane);        \
    }                                                                      \
    ctc_gath(PN, bufn, e4);                                                \
    ctc_upd(a, PC, skipm, lane);                                           \
  }

__global__ __launch_bounds__(512) void ctc_main(
    const float* __restrict__ lp, const int* __restrict__ ilen,
    const int* __restrict__ tgt, const int* __restrict__ tlen,
    int T, int N, int C, int L,
    double* __restrict__ ws_lse,   // [N*6] per-helper-wave lse partial sums
    double* __restrict__ ws_ll) {  // [N]   raw log A(end) + logscale
  const int n = blockIdx.x;
  const int tid = threadIdx.x;
  const int wid = tid >> 6;
  const int lane = tid & 63;
  const int NC = N * C;
  const int Tn = ilen[n];

  if (wid == 4) return;  // keep wave0's SIMD free (waves 0 and 4 share SIMD0)

  if (wid != 0) {
    // ---- helper waves: sum of per-row logsumexp over C, rows strided by 6 ----
    const int h = (wid < 4) ? (wid - 1) : (wid - 2);  // 0..5
    const float* base = lp + (size_t)n * C + 2 * lane;
    double acc = 0.0;
    for (int t = h; t < Tn; t += 6) {
      float2 v = *(const float2*)(base + (size_t)t * NC);
      float m = fmaxf(v.x, v.y);
#pragma unroll
      for (int off = 32; off; off >>= 1) m = fmaxf(m, __shfl_xor(m, off));
      float s = __expf(v.x - m) + __expf(v.y - m);
#pragma unroll
      for (int off = 32; off; off >>= 1) s += __shfl_xor(s, off);
      acc += (double)m + log((double)s);
    }
    if (lane == 0) ws_lse[n * 6 + h] = acc;
    return;
  }

  // ---- wave 0: the serial alpha chain (fp64 linear space, pow2 renorm) ----
  __shared__ float rb[2 * RBW];  // 2 ping-pong row buffers, [128] is a zero slot
  __shared__ double adump[64 * KST];

  const int tlv = tlen[n];
  const int gend = 2 * tlv;  // last live state; states beyond never affect output
  const int* tg = tgt + (size_t)n * L;

  // zero slots (so invalid-state gathers return exactly 0)
  if (lane == 0) { rb[128] = 0.f; rb[RBW + 128] = 0.f; }

  int e4[KST];
  double skipm[KST];
#pragma unroll
  for (int s = 0; s < KST; ++s) {
    int g = lane * KST + s;
    int eidx = CTC_BLANK;
    double sk = 0.;
    if (g & 1) {
      int k = (g - 1) >> 1;
      int kc = (k < L) ? k : (L - 1);
      eidx = tg[kc];
      if (g >= 3) {
        int kp = k - 1;
        if (kp > L - 1) kp = L - 1;
        int ep = tg[kp];
        sk = (eidx != ep && eidx != CTC_BLANK) ? 1. : 0.;
      }
    }
    if (g > gend) eidx = 128;  // phantom/unneeded state -> gathers 0 forever
    e4[s] = eidx;
    skipm[s] = sk;
  }

  const float* lpn = lp + (size_t)n * C;
  const int Tlast = T - 1;

  // stage row 0 (buf0) and row 1 (buf1)
  {
    float2 v0 = *(const float2*)(lpn + 2 * lane);
    rb[2 * lane] = __expf(v0.x);
    rb[2 * lane + 1] = __expf(v0.y);
    int t1 = (1 > Tlast) ? Tlast : 1;
    float2 v1 = *(const float2*)(lpn + (size_t)t1 * NC + 2 * lane);
    rb[RBW + 2 * lane] = __expf(v1.x);
    rb[RBW + 2 * lane + 1] = __expf(v1.y);
  }

  // init alpha from row 0: A[0]=p(ext0), A[1]=p(ext1), rest 0
  double a[KST];
#pragma unroll
  for (int s = 0; s < KST; ++s) {
    int g = lane * KST + s;
    float p = rb[e4[s]];
    a[s] = (g < 2) ? (double)p : 0.;
  }

  // gather p for step t=1 (row 1) into pA
  float pA[KST], pB[KST];
  ctc_gath(pA, rb + RBW, e4);

  // prefetch rows 2..9
  float2 pre[8];
#pragma unroll
  for (int j = 0; j < 8; ++j) {
    int tl_ = 2 + j;
    if (tl_ > Tlast) tl_ = Tlast;
    pre[j] = *(const float2*)(lpn + (size_t)tl_ * NC + 2 * lane);
  }

  long long Esum = 0;
  int t0 = 1;  // invariant: t0 == 1 (mod 8) always

  for (; t0 + 8 <= Tn; t0 += 8) {
    CTC_STEP(0, pA, pB)
    CTC_STEP(1, pB, pA)
    CTC_STEP(2, pA, pB)
    CTC_STEP(3, pB, pA)
    CTC_STEP(4, pA, pB)
    CTC_STEP(5, pB, pA)
    CTC_STEP(6, pA, pB)
    CTC_STEP(7, pB, pA)
    // renorm every 8 steps: exact power-of-two rescale, integer exponent track
    double m = a[0];
#pragma unroll
    for (int s = 1; s < KST; ++s) m = fmax(m, a[s]);
#pragma unroll
    for (int off = 32; off; off >>= 1) m = fmax(m, __shfl_xor(m, off));
    int E = (m > 0.) ? ilogb(m) : 0;
    double scale = ldexp(1.0, -E);  // exact
    Esum += E;
#pragma unroll
    for (int s = 0; s < KST; ++s) a[s] *= scale;  // exact (pow2 multiply)
  }
  // tail (< 8 steps), t0 stays == 1 mod 8 so CTC_STEP buffer parities stay valid
  if (t0 + 0 < Tn) CTC_STEP(0, pA, pB)
  if (t0 + 1 < Tn) CTC_STEP(1, pB, pA)
  if (t0 + 2 < Tn) CTC_STEP(2, pA, pB)
  if (t0 + 3 < Tn) CTC_STEP(3, pB, pA)
  if (t0 + 4 < Tn) CTC_STEP(4, pA, pB)
  if (t0 + 5 < Tn) CTC_STEP(5, pB, pA)
  if (t0 + 6 < Tn) CTC_STEP(6, pA, pB)

  // epilogue: dump alpha, read the two end states
#pragma unroll
  for (int s = 0; s < KST; ++s) adump[lane * KST + s] = a[s];
  if (lane == 0) {
    int end = gend;
    int i2 = (end > 0) ? (end - 1) : (2 * L);  // python wrap for end==0
    double Ae = adump[end] + adump[i2];
    ws_ll[n] = log(Ae) + (double)Esum * 0.69314718055994530942;
  }
}

__global__ void ctc_final(const double* __restrict__ ws_lse,
                          const double* __restrict__ ws_ll,
                          float* __restrict__ out, int N) {
  __shared__ double sred[128];
  const int i = threadIdx.x;
  double l = 0.0;
  if (i < N) {
    double denom = 0.0;
#pragma unroll
    for (int h = 0; h < 6; ++h) denom += ws_lse[i * 6 + h];
    double ll = ws_ll[i] - denom;
    double ls = -ll;
    if (!isfinite(ls) || fabs(ls) >= 1e29) ls = 0.0;
    l = ls;
  }
  sred[i] = l;
  __syncthreads();
#pragma unroll
  for (int off = 64; off > 0; off >>= 1) {
    if (i < off) sred[i] += sred[i + off];
    __syncthreads();
  }
  if (i == 0) out[0] = (float)sred[0];
}

extern "C" void kernel_launch(void* const* d_in, const int* in_sizes, int n_in,
                              void* d_out, int out_size, void* d_ws, size_t ws_size,
                              hipStream_t stream) {
  (void)n_in; (void)out_size; (void)ws_size;
  const float* lp = (const float*)d_in[0];
  const int* ilen = (const int*)d_in[1];
  const int* tgt = (const int*)d_in[2];
  const int* tlen = (const int*)d_in[3];

  const int N = in_sizes[1];            // 128
  const int L = in_sizes[2] / N;        // 256
  const int C = 128;                    // classes (fixed by problem)
  const int T = in_sizes[0] / (N * C);  // 4000

  double* ws_lse = (double*)d_ws;              // N*6 doubles
  double* ws_ll = ws_lse + (size_t)N * 6;      // N doubles

  ctc_main<<<N, 512, 0, stream>>>(lp, ilen, tgt, tlen, T, N, C, L, ws_lse, ws_ll);
  ctc_final<<<1, 128, 0, stream>>>(ws_lse, ws_ll, (float*)d_out, N);
}

// Round 4
// 480.931 us; speedup vs baseline: 1.5938x; 1.5938x over previous
//
#include <hip/hip_runtime.h>
#include <math.h>

#define CTC_BLANK 1
#define RBW 132  // row-buffer stride (floats): 128 classes + zero slot at [128]

struct Pv { double pb, p1, p3, p5, p7; };

// gather emission probs for this lane's slots from staged f32 row -> f64
#define GATH(P, boff)                              \
  {                                                \
    P.pb = (double)rb[(boff) + CTC_BLANK];         \
    P.p1 = (double)rb[(boff) + i1];                \
    P.p3 = (double)rb[(boff) + i3];                \
    P.p5 = (double)rb[(boff) + i5];                \
    P.p7 = (double)rb[(boff) + i7];                \
  }

// One step (row t = t0+J): stage row t+1 from prefetch, refill prefetch (t+9),
// gather p for next step, update alpha (8 slots + a8) with p from last step.
// Halo: HMI = prev-lane a[7] @ t-1 (bpermute issued last step); HMO issued for next.
#define CTC_STEP(J, PC, PN, HMI, HMO)                                  \
  {                                                                    \
    const int boff = RBW * ((J) & 1);                                  \
    float ex = __expf(pre[J].x), ey = __expf(pre[J].y);                \
    *(float2*)&rb[boff + 2 * lane] = make_float2(ex, ey);              \
    {                                                                  \
      int tl_ = t0 + (J) + 9;                                          \
      if (tl_ > Tlast) tl_ = Tlast;                                    \
      pre[J] = *(const float2*)(lpn + (size_t)tl_ * NC + 2 * lane);    \
    }                                                                  \
    GATH(PN, boff);                                                    \
    double t7o = a[7];                                                 \
    a8 = (a8 + t7o * m63) * PC.pb;                                     \
    a[7] = fma(sk7, a[5], a[7] + a[6]) * PC.p7;                        \
    HMO = __shfl_up(a[7], 1);                                          \
    a[6] = (a[6] + a[5]) * PC.pb;                                      \
    a[5] = fma(sk5, a[3], a[5] + a[4]) * PC.p5;                        \
    a[4] = (a[4] + a[3]) * PC.pb;                                      \
    a[3] = fma(sk3, a[1], a[3] + a[2]) * PC.p3;                        \
    a[2] = (a[2] + a[1]) * PC.pb;                                      \
    double hh = HMI * lz;                                              \
    a[1] = fma(sk1, hh, a[1] + a[0]) * PC.p1;                          \
    a[0] = (a[0] + hh) * PC.pb;                                        \
  }

__global__ __launch_bounds__(512) void ctc_main(
    const float* __restrict__ lp, const int* __restrict__ ilen,
    const int* __restrict__ tgt, const int* __restrict__ tlen,
    int T, int N, int C, int L,
    double* __restrict__ ws_lse,   // [N*6] per-helper-wave lse partials
    double* __restrict__ ws_ll) {  // [N]   raw log A(end) + exponent track
  const int n = blockIdx.x;
  const int tid = threadIdx.x;
  const int wid = tid >> 6;
  const int lane = tid & 63;
  const int NC = N * C;
  const int Tn = ilen[n];

  if (wid == 4) return;  // keep wave0's SIMD to itself (waves 0,4 share SIMD0)

  if (wid != 0) {
    // ---- helper waves: one t-row PER LANE; no cross-lane work until the end ----
    const int h = (wid < 4) ? (wid - 1) : (wid - 2);  // 0..5
    const int per = (T + 5) / 6;
    const int tb = h * per;
    int te = tb + per;
    if (te > Tn) te = Tn;
    const float* basen = lp + (size_t)n * C;
    double acc = 0.0;
    for (int t0b = tb; t0b < te; t0b += 64) {
      int t = t0b + lane;
      if (t < te) {
        const float4* rp = (const float4*)(basen + (size_t)t * NC);
        float sx = 0.f, sy = 0.f, sz = 0.f, sw = 0.f;
        const int c4n = C >> 2;
#pragma unroll 8
        for (int c4 = 0; c4 < c4n; ++c4) {
          float4 v = rp[c4];
          sx += __expf(v.x); sy += __expf(v.y);
          sz += __expf(v.z); sw += __expf(v.w);
        }
        acc += log((double)((sx + sy) + (sz + sw)));
      }
    }
#pragma unroll
    for (int off = 32; off; off >>= 1) acc += __shfl_xor(acc, off);
    if (lane == 0) ws_lse[n * 6 + h] = acc;
    return;
  }

  // ---- wave 0: serial alpha chain, 8 states/lane + state 512 on lane 63 ----
  __shared__ float rb[2 * RBW];
  __shared__ double adump[513];

  const int tlv = tlen[n];
  const int gend = 2 * tlv;
  const int* tg = tgt + (size_t)n * L;

  if (lane == 0) { rb[128] = 0.f; rb[RBW + 128] = 0.f; }  // zero slots

  // per-lane static data: odd slots s=1,3,5,7 -> class index + skip flag
  int i1, i3, i5, i7;
  double sk1, sk3, sk5, sk7;
  {
    int idx[4]; double sk[4];
#pragma unroll
    for (int q = 0; q < 4; ++q) {
      int s = 2 * q + 1;
      int g = lane * 8 + s;
      int k = (g - 1) >> 1;
      int kc = (k < L) ? k : (L - 1);
      int eidx = tg[kc];
      double skv = 0.;
      if (g >= 3) {
        int kp = k - 1; if (kp > L - 1) kp = L - 1;
        int ep = tg[kp];
        skv = (eidx != ep && eidx != CTC_BLANK) ? 1. : 0.;
      }
      if (g > gend) eidx = 128;  // dead state -> gathers exact 0
      idx[q] = eidx; sk[q] = skv;
    }
    i1 = idx[0]; i3 = idx[1]; i5 = idx[2]; i7 = idx[3];
    sk1 = sk[0]; sk3 = sk[1]; sk5 = sk[2]; sk7 = sk[3];
  }
  const double m63 = (lane == 63) ? 1.0 : 0.0;
  const double lz  = (lane == 0) ? 0.0 : 1.0;

  const float* lpn = lp + (size_t)n * C;
  const int Tlast = T - 1;

  // stage row 0 -> buf0, row 1 -> buf1
  {
    float2 v0 = *(const float2*)(lpn + 2 * lane);
    *(float2*)&rb[2 * lane] = make_float2(__expf(v0.x), __expf(v0.y));
    int t1 = (1 > Tlast) ? Tlast : 1;
    float2 v1 = *(const float2*)(lpn + (size_t)t1 * NC + 2 * lane);
    *(float2*)&rb[RBW + 2 * lane] = make_float2(__expf(v1.x), __expf(v1.y));
  }

  Pv pA, pB;
  // init alpha from row 0: states 0,1 live (lane 0 slots 0,1)
  double a[8], a8 = 0.0;
  GATH(pA, 0);
  a[0] = (lane == 0) ? pA.pb : 0.0;
  a[1] = (lane == 0) ? pA.p1 : 0.0;
#pragma unroll
  for (int s = 2; s < 8; ++s) a[s] = 0.0;
  GATH(pA, RBW);  // p for step t=1 (row 1)

  // prefetch rows 2..9
  float2 pre[8];
#pragma unroll
  for (int j = 0; j < 8; ++j) {
    int tl_ = 2 + j; if (tl_ > Tlast) tl_ = Tlast;
    pre[j] = *(const float2*)(lpn + (size_t)tl_ * NC + 2 * lane);
  }

  double hA = 0.0, hB = 0.0;  // pipelined halo (prev-lane a[7] of previous step)
  long long Esum = 0;
  int t0 = 1;  // invariant: t0 == 1 (mod 8)

  for (; t0 + 8 <= Tn; t0 += 8) {
    CTC_STEP(0, pA, pB, hA, hB)
    CTC_STEP(1, pB, pA, hB, hA)
    CTC_STEP(2, pA, pB, hA, hB)
    CTC_STEP(3, pB, pA, hB, hA)
    CTC_STEP(4, pA, pB, hA, hB)
    CTC_STEP(5, pB, pA, hB, hA)
    CTC_STEP(6, pA, pB, hA, hB)
    CTC_STEP(7, pB, pA, hB, hA)
    // renorm every 8 steps: sampled wave max on scalar pipe, exact pow2 rescale
    double m = fmax(a[0], a[1]);
    m = fmax(m, fmax(a[2], a[3]));
    m = fmax(m, fmax(a[4], a[5]));
    m = fmax(m, fmax(a[6], a[7]));
    m = fmax(m, a8);
    int hi = __double2hiint(m);
    int mx = __builtin_amdgcn_readlane(hi, 0);
#pragma unroll
    for (int l = 4; l < 64; l += 4) {
      int v = __builtin_amdgcn_readlane(hi, l);
      mx = (v > mx) ? v : mx;
    }
    int E = ((mx >> 20) & 0x7ff) - 1023;
    double sc = ldexp(1.0, -E);  // exact
    Esum += E;
#pragma unroll
    for (int s = 0; s < 8; ++s) a[s] *= sc;
    a8 *= sc;
    hA *= sc;  // pending halo must carry the same scale
  }
  // tail (< 8 steps); guards are a strict prefix so halo ping-pong stays valid
  if (t0 + 0 < Tn) CTC_STEP(0, pA, pB, hA, hB)
  if (t0 + 1 < Tn) CTC_STEP(1, pB, pA, hB, hA)
  if (t0 + 2 < Tn) CTC_STEP(2, pA, pB, hA, hB)
  if (t0 + 3 < Tn) CTC_STEP(3, pB, pA, hB, hA)
  if (t0 + 4 < Tn) CTC_STEP(4, pA, pB, hA, hB)
  if (t0 + 5 < Tn) CTC_STEP(5, pB, pA, hB, hA)
  if (t0 + 6 < Tn) CTC_STEP(6, pA, pB, hA, hB)

  // epilogue
#pragma unroll
  for (int s = 0; s < 8; ++s) adump[lane * 8 + s] = a[s];
  if (lane == 63) adump[512] = a8;
  if (lane == 0) {
    int end = gend;
    int i2 = (end > 0) ? (end - 1) : (2 * L);
    double Ae = adump[end] + adump[i2];
    ws_ll[n] = log(Ae) + (double)Esum * 0.69314718055994530942;
  }
}

__global__ void ctc_final(const double* __restrict__ ws_lse,
                          const double* __restrict__ ws_ll,
                          float* __restrict__ out, int N) {
  __shared__ double sred[128];
  const int i = threadIdx.x;
  double l = 0.0;
  if (i < N) {
    double denom = 0.0;
#pragma unroll
    for (int h = 0; h < 6; ++h) denom += ws_lse[i * 6 + h];
    double ll = ws_ll[i] - denom;
    double ls = -ll;
    if (!isfinite(ls) || fabs(ls) >= 1e29) ls = 0.0;
    l = ls;
  }
  sred[i] = l;
  __syncthreads();
#pragma unroll
  for (int off = 64; off > 0; off >>= 1) {
    if (i < off) sred[i] += sred[i + off];
    __syncthreads();
  }
  if (i == 0) out[0] = (float)sred[0];
}

extern "C" void kernel_launch(void* const* d_in, const int* in_sizes, int n_in,
                              void* d_out, int out_size, void* d_ws, size_t ws_size,
                              hipStream_t stream) {
  (void)n_in; (void)out_size; (void)ws_size;
  const float* lp = (const float*)d_in[0];
  const int* ilen = (const int*)d_in[1];
  const int* tgt = (const int*)d_in[2];
  const int* tlen = (const int*)d_in[3];

  const int N = in_sizes[1];            // 128
  const int L = in_sizes[2] / N;        // 256
  const int C = 128;                    // classes (fixed by problem)
  const int T = in_sizes[0] / (N * C);  // 4000

  double* ws_lse = (double*)d_ws;           // N*6 doubles
  double* ws_ll = ws_lse + (size_t)N * 6;   // N doubles

  ctc_main<<<N, 512, 0, stream>>>(lp, ilen, tgt, tlen, T, N, C, L, ws_lse, ws_ll);
  ctc_final<<<1, 128, 0, stream>>>(ws_lse, ws_ll, (float*)d_out, N);
}